// Round 7
// baseline (657.984 us; speedup 1.0000x reference)
//
#include <hip/hip_runtime.h>

typedef _Float16 half8 __attribute__((ext_vector_type(8)));
typedef float    float4v __attribute__((ext_vector_type(4)));
typedef unsigned int u32;

#define NQ 8
#define KCODES 4096
#define DIMS 128
#define BATCH 8
#define SEQ 4096
#define ROWS (BATCH*SEQ)            // 32768
#define TM 64                       // rows per block (B-traffic = ROWS/TM * 8MB)
#define NBLK (ROWS/TM)              // 512
#define RESPAD 132                  // res row stride (floats), 16B-aligned
#define CANDROW 67                  // cand row stride (uints)
#define OUT_ELEMS (BATCH*DIMS*SEQ)  // 4194304
#define IDX_ELEMS (BATCH*SEQ*NQ)    // 262144
#define LOSS_DIV (1.0f/33554432.0f) // 1/(Q*B*N*D)
#define FRAGQ ((size_t)4*256*64*8)  // halves per q-stage of bhi
#define SBIAS 384.0f                // key bias: keys = dot - csq/2 + 384, in ~[240,450] > 0
#define WIN 2.0f                    // refine window (>> 2*(f16 err + 0.125 pack trunc))

__device__ __forceinline__ unsigned umax_(unsigned a, unsigned b){ return a>b?a:b; }
__device__ __forceinline__ unsigned umin_(unsigned a, unsigned b){ return a<b?a:b; }

// async global->LDS DMA, 16 B/lane. LDS dest is wave-uniform base + lane*16;
// global src is per-lane. Zero VGPR cost -> regalloc cannot collapse the pipeline.
__device__ __forceinline__ void gload16(const void* g, void* l) {
    __builtin_amdgcn_global_load_lds(
        (const __attribute__((address_space(1))) u32*)g,
        (__attribute__((address_space(3))) u32*)l, 16, 0, 0);
}

// ---------------- prep: csq[q][k] = sum_d cb^2 ; cinit = 384 - csq/2 ----------------
__global__ void prep_csq(const float* __restrict__ cb, float* __restrict__ csq,
                         float* __restrict__ cinit) {
    int c = blockIdx.x * 256 + threadIdx.x;   // q*4096+k
    const float4* p = (const float4*)(cb + (size_t)c * DIMS);
    float s = 0.f;
#pragma unroll
    for (int i = 0; i < 32; ++i) {
        float4 v = p[i];
        s += v.x * v.x + v.y * v.y + v.z * v.z + v.w * v.w;
    }
    csq[c] = s;
    cinit[c] = SBIAS - 0.5f * s;
}

// ---------------- prep: codebook -> f16 hi MFMA B-fragments (screen only) ----------------
// mfma_f32_16x16x32_f16 B-operand: lane l holds B[k=(l>>4)*8+j][n=l&15], j=0..7.
// Storage: frag g = ((q*4+kb)*256+nt)*64+lane at bhi + g*8 halves.
__global__ void prep_frags(const float* __restrict__ cb, _Float16* __restrict__ bhi,
                           float* __restrict__ loss_accum) {
    int g = blockIdx.x * 256 + threadIdx.x;   // 524288 total
    if (g == 0) loss_accum[0] = 0.f;
    int lane = g & 63;
    int nt   = (g >> 6) & 255;
    int kb   = (g >> 14) & 3;
    int q    = g >> 16;
    int code = nt * 16 + (lane & 15);
    int k0   = kb * 32 + ((lane >> 4) * 8);
    const float* src = cb + ((size_t)q * KCODES + code) * DIMS + k0;
    float4 v0 = *(const float4*)(src);
    float4 v1 = *(const float4*)(src + 4);
    half8 h;
    h[0] = (_Float16)v0.x; h[1] = (_Float16)v0.y; h[2] = (_Float16)v0.z; h[3] = (_Float16)v0.w;
    h[4] = (_Float16)v1.x; h[5] = (_Float16)v1.y; h[6] = (_Float16)v1.z; h[7] = (_Float16)v1.w;
    *(half8*)(bhi + (size_t)g * 8) = h;
}

// ---------------- main: one screen sub-tile (16 codes), LDS-staged B ----------------
// Reads tile t from stg buf (t&1), issues DMA for t+1 into buf (t+1)&1, computes
// 16 MFMA + best-2 insert, then drains vmcnt so t+1 is ready for next sub-iter.
__device__ __forceinline__ void sub_tile(
        int j, int t, int ntBase, int lane, int csel, float csCur,
        const _Float16* __restrict__ bq, char* stgw,
        const half8 (&ahi)[4][4], unsigned (&p1)[4][4], unsigned (&p2)[4][4]) {
    int nt = ntBase + t;
    // ds_read current tile (4 x b128, lane-major 16B: conflict-free phase pattern)
    const half8* sp = (const half8*)(stgw + ((t & 1) << 12) + (lane << 4));
    half8 b0 = sp[0], b1 = sp[64], b2 = sp[128], b3 = sp[192];

    // stage next tile (issued before compute -> ~250 cyc cover)
    {
        int ntn = ntBase + ((t + 1) & 63);
        char* dst = stgw + (((t + 1) & 1) << 12);
#pragma unroll
        for (int kb = 0; kb < 4; ++kb) {
            const _Float16* g = bq + (((size_t)(kb * 256 + ntn) * 64 + lane) << 3);
            gload16(g, dst + (kb << 10));
        }
    }

    float csv = __shfl(csCur, j * 16 + csel, 64);   // cinit for this tile's column

    float4v acc[4];
#pragma unroll
    for (int mt = 0; mt < 4; ++mt) { acc[mt][0]=0.f; acc[mt][1]=0.f; acc[mt][2]=0.f; acc[mt][3]=0.f; }
    __builtin_amdgcn_s_setprio(1);
#pragma unroll
    for (int mt = 0; mt < 4; ++mt) acc[mt] = __builtin_amdgcn_mfma_f32_16x16x32_f16(ahi[mt][0], b0, acc[mt], 0, 0, 0);
#pragma unroll
    for (int mt = 0; mt < 4; ++mt) acc[mt] = __builtin_amdgcn_mfma_f32_16x16x32_f16(ahi[mt][1], b1, acc[mt], 0, 0, 0);
#pragma unroll
    for (int mt = 0; mt < 4; ++mt) acc[mt] = __builtin_amdgcn_mfma_f32_16x16x32_f16(ahi[mt][2], b2, acc[mt], 0, 0, 0);
#pragma unroll
    for (int mt = 0; mt < 4; ++mt) acc[mt] = __builtin_amdgcn_mfma_f32_16x16x32_f16(ahi[mt][3], b3, acc[mt], 0, 0, 0);
    __builtin_amdgcn_s_setprio(0);

    // key = dot + (384 - csq/2); pack idx in low 12 mantissa bits; best-2 via umin/umax
    unsigned idxv = (unsigned)(nt * 16 + csel);
#pragma unroll
    for (int mt = 0; mt < 4; ++mt)
#pragma unroll
        for (int r = 0; r < 4; ++r) {
            float key = acc[mt][r] + csv;
            unsigned p  = (__float_as_uint(key) & 0xFFFFF000u) | idxv;
            unsigned t1 = umin_(p1[mt][r], p);
            p1[mt][r]   = umax_(p1[mt][r], p);
            p2[mt][r]   = umax_(p2[mt][r], t1);
        }

    // drain DMA for tile t+1; fence so next sub-iter's ds_read can't hoist above
    asm volatile("s_waitcnt vmcnt(0)" ::: "memory");
    __builtin_amdgcn_sched_barrier(0);
}

// (256,2): VGPR cap 256 (generous; tight caps spill — round 2). Grid 512 pins
// 2 blocks/CU. B-prefetch lives in LDS via global_load_lds (zero VGPRs), so
// regalloc cannot collapse it (round 6 failure mode).
__launch_bounds__(256, 2)
__global__ void rvq_main(const float* __restrict__ x, const float* __restrict__ cb,
                         const _Float16* __restrict__ bhi,
                         const float* __restrict__ csq, const float* __restrict__ cinit,
                         float* __restrict__ out, float* __restrict__ loss_accum) {
    __shared__ float res[TM][RESPAD];               // residual fp32 (33792 B)
    __shared__ __align__(16) char stg[4][8192];     // per-wave B dbuf (32768 B)
    __shared__ float fbin[TM];                      // final best idx per row
    // overlays on stg (dead during tile loop / alive after, barrier-separated):
    unsigned (*cand)[CANDROW] = reinterpret_cast<unsigned (*)[CANDROW]>(&stg[0][0]); // 17152 B
    float* red = reinterpret_cast<float*>(&stg[0][0] + 20480);                       // 1024 B
    // static LDS = 66816 B -> 2 blocks/CU

    int tid  = threadIdx.x;
    int lane = tid & 63;
    int wv   = tid >> 6;
    int csel = lane & 15;
    int r0   = blockIdx.x * TM;
    int b    = r0 >> 12;                // / SEQ
    int n0   = r0 & (SEQ - 1);
    const float* xb = x + (size_t)b * DIMS * SEQ + n0;

    // load x[b][d][n0..n0+63] into res[n][d]
    {
        int d = tid >> 1, half = (tid & 1) * 32;
        const float* src = xb + (size_t)d * SEQ + half;
#pragma unroll
        for (int t4 = 0; t4 < 8; ++t4) {
            float4 v = *(const float4*)(src + t4 * 4);
            res[half + t4 * 4 + 0][d] = v.x;
            res[half + t4 * 4 + 1][d] = v.y;
            res[half + t4 * 4 + 2][d] = v.z;
            res[half + t4 * 4 + 3][d] = v.w;
        }
    }

    float lossacc = 0.f;
    int ntBase = wv * 64;
    char* stgw = &stg[wv][0];

    for (int q = 0; q < NQ; ++q) {
        __syncthreads();   // res stable; prev q's cand reads done

        const _Float16* bq   = bhi + (size_t)q * FRAGQ;
        const float*    cinq = cinit + q * KCODES;
        const float*    csqq = csq + q * KCODES;

        // prologue: first cinit chunk + DMA tile 0 (overlaps ahi build below)
        float csCur = cinq[wv * 1024 + lane];
        {
#pragma unroll
            for (int kb = 0; kb < 4; ++kb) {
                const _Float16* g = bq + (((size_t)(kb * 256 + ntBase) * 64 + lane) << 3);
                gload16(g, stgw + (kb << 10));
            }
        }

        // build A fragments (hi f16) from res — ~600 cyc, covers the T0 DMA
        half8 ahi[4][4];
#pragma unroll
        for (int mt = 0; mt < 4; ++mt)
#pragma unroll
        for (int kb = 0; kb < 4; ++kb) {
            int row = mt * 16 + csel;
            int k0  = kb * 32 + (lane >> 4) * 8;
            float4 v0 = *(const float4*)&res[row][k0];
            float4 v1 = *(const float4*)&res[row][k0 + 4];
            half8 h;
            h[0] = (_Float16)v0.x; h[1] = (_Float16)v0.y; h[2] = (_Float16)v0.z; h[3] = (_Float16)v0.w;
            h[4] = (_Float16)v1.x; h[5] = (_Float16)v1.y; h[6] = (_Float16)v1.z; h[7] = (_Float16)v1.w;
            ahi[mt][kb] = h;
        }

        unsigned p1[4][4], p2[4][4];
#pragma unroll
        for (int mt = 0; mt < 4; ++mt)
#pragma unroll
        for (int r = 0; r < 4; ++r) { p1[mt][r] = 0u; p2[mt][r] = 0u; }

        asm volatile("s_waitcnt vmcnt(0)" ::: "memory");   // T0 + csCur landed
        __builtin_amdgcn_sched_barrier(0);

        // 64 tiles, 4 per cinit chunk; wave-private LDS double-buffer
        for (int ii = 0; ii < 16; ++ii) {
            float csNext = cinq[wv * 1024 + (((ii + 1) & 15) << 6) + lane];
            sub_tile(0, ii * 4 + 0, ntBase, lane, csel, csCur, bq, stgw, ahi, p1, p2);
            sub_tile(1, ii * 4 + 1, ntBase, lane, csel, csCur, bq, stgw, ahi, p1, p2);
            sub_tile(2, ii * 4 + 2, ntBase, lane, csel, csCur, bq, stgw, ahi, p1, p2);
            sub_tile(3, ii * 4 + 3, ntBase, lane, csel, csCur, bq, stgw, ahi, p1, p2);
            csCur = csNext;
        }

        __syncthreads();   // all waves done with stg before cand overlay is written

        // pair-merge best-2 across (lane, lane^1) -> top-2-of-128 slices.
        // Sorted pairs A,B: n1=max(a1,b1); n2=max(min(a1,b1), max(a2,b2)).
#pragma unroll
        for (int mt = 0; mt < 4; ++mt)
#pragma unroll
        for (int r = 0; r < 4; ++r) {
            unsigned a1 = p1[mt][r], a2 = p2[mt][r];
            unsigned b1 = (unsigned)__shfl_xor((int)a1, 1, 64);
            unsigned b2 = (unsigned)__shfl_xor((int)a2, 1, 64);
            unsigned n1 = umax_(a1, b1);
            unsigned n2 = umax_(umin_(a1, b1), umax_(a2, b2));
            if ((lane & 1) == 0) {
                int row = mt * 16 + (lane >> 4) * 4 + r;
                int col = wv * 16 + (csel >> 1) * 2;
                cand[row][col]     = n1;
                cand[row][col + 1] = n2;
            }
        }
        __syncthreads();

        // exact f32 refine: 4 threads/row scan 16 entries; entries within WIN
        // of the row max get an exact f32 dot (res in LDS, cb row in L2).
        {
            int row = tid >> 2, s = tid & 3;
            const unsigned* cp = &cand[row][s * 16];
            unsigned m = 0;
#pragma unroll
            for (int k = 0; k < 16; ++k) m = umax_(m, cp[k]);
            m = umax_(m, (unsigned)__shfl_xor((int)m, 1, 64));
            m = umax_(m, (unsigned)__shfl_xor((int)m, 2, 64));
            float thr = __uint_as_float(m) - WIN;
            float bk = -3.4e38f;
            int   bi = KCODES;
            const float4* rv = (const float4*)&res[row][0];
            for (int k = 0; k < 16; ++k) {
                unsigned e = cp[k];
                if (__uint_as_float(e) >= thr) {
                    int idx = (int)(e & 0xFFFu);
                    const float4* cv = (const float4*)(cb + ((size_t)q * KCODES + idx) * DIMS);
                    float acc = 0.f;
#pragma unroll
                    for (int jj = 0; jj < 32; ++jj) {
                        float4 c4 = cv[jj];
                        float4 r4 = rv[jj];
                        acc = fmaf(r4.x, c4.x, acc);
                        acc = fmaf(r4.y, c4.y, acc);
                        acc = fmaf(r4.z, c4.z, acc);
                        acc = fmaf(r4.w, c4.w, acc);
                    }
                    float key = acc - 0.5f * csqq[idx];
                    if (key > bk || (key == bk && idx < bi)) { bk = key; bi = idx; }
                }
            }
#pragma unroll
            for (int mask = 1; mask <= 2; mask <<= 1) {
                float ok = __shfl_xor(bk, mask, 64);
                int   oi = __shfl_xor(bi, mask, 64);
                if (ok > bk || (ok == bk && oi < bi)) { bk = ok; bi = oi; }
            }
            if (s == 0) {
                fbin[row] = (float)bi;
                out[OUT_ELEMS + (size_t)(r0 + row) * NQ + q] = (float)bi;  // index output
            }
        }
        __syncthreads();

        // residual update + commitment loss; contiguous 32-float chunk per thread
        {
            int row = tid >> 2, j = tid & 3;
            int bi = (int)fbin[row];
            const float* cv = cb + ((size_t)q * KCODES + bi) * DIMS + j * 32;
            float* rp = &res[row][j * 32];
#pragma unroll
            for (int t = 0; t < 8; ++t) {
                float4 c4 = *(const float4*)(cv + t * 4);
                float4 r4 = *(const float4*)(rp + t * 4);
                r4.x -= c4.x; lossacc = fmaf(r4.x, r4.x, lossacc);
                r4.y -= c4.y; lossacc = fmaf(r4.y, r4.y, lossacc);
                r4.z -= c4.z; lossacc = fmaf(r4.z, r4.z, lossacc);
                r4.w -= c4.w; lossacc = fmaf(r4.w, r4.w, lossacc);
                *(float4*)(rp + t * 4) = r4;
            }
        }
    }

    // loss reduction (red overlays stg; all stage/cand use is done)
    __syncthreads();
    red[tid] = lossacc;
    __syncthreads();
    for (int s = 128; s > 0; s >>= 1) {
        if (tid < s) red[tid] += red[tid + s];
        __syncthreads();
    }
    if (tid == 0) atomicAdd(loss_accum, red[0]);

    // quantized output: out = x - final_residual
    {
        int d = tid >> 1, half = (tid & 1) * 32;
        const float* src = xb + (size_t)d * SEQ + half;
        float* dst = out + (size_t)b * DIMS * SEQ + (size_t)d * SEQ + n0 + half;
#pragma unroll
        for (int t4 = 0; t4 < 8; ++t4) {
            float4 v = *(const float4*)(src + t4 * 4);
            v.x -= res[half + t4 * 4 + 0][d];
            v.y -= res[half + t4 * 4 + 1][d];
            v.z -= res[half + t4 * 4 + 2][d];
            v.w -= res[half + t4 * 4 + 3][d];
            *(float4*)(dst + t4 * 4) = v;
        }
    }
}

__global__ void finish_loss(const float* __restrict__ loss_accum, float* __restrict__ out) {
    out[OUT_ELEMS + IDX_ELEMS] = loss_accum[0] * LOSS_DIV;
}

extern "C" void kernel_launch(void* const* d_in, const int* in_sizes, int n_in,
                              void* d_out, int out_size, void* d_ws, size_t ws_size,
                              hipStream_t stream) {
    const float* x  = (const float*)d_in[0];
    const float* cb = (const float*)d_in[1];
    float* out = (float*)d_out;
    char*  ws  = (char*)d_ws;

    float*     loss_accum = (float*)ws;
    float*     csq   = (float*)(ws + 256);
    float*     cinit = (float*)(ws + 256 + 131072);
    _Float16*  bhi   = (_Float16*)(ws + 256 + 262144);

    hipLaunchKernelGGL(prep_csq,   dim3(128),  dim3(256), 0, stream, cb, csq, cinit);
    hipLaunchKernelGGL(prep_frags, dim3(2048), dim3(256), 0, stream, cb, bhi, loss_accum);
    hipLaunchKernelGGL(rvq_main,   dim3(NBLK), dim3(256), 0, stream,
                       x, cb, bhi, csq, cinit, out, loss_accum);
    hipLaunchKernelGGL(finish_loss, dim3(1), dim3(1), 0, stream, loss_accum, out);
}

// Round 8
// 575.534 us; speedup vs baseline: 1.1433x; 1.1433x over previous
//
#include <hip/hip_runtime.h>

typedef _Float16 half8 __attribute__((ext_vector_type(8)));
typedef float    float4v __attribute__((ext_vector_type(4)));
typedef unsigned int u32;

#define NQ 8
#define KCODES 4096
#define DIMS 128
#define BATCH 8
#define SEQ 4096
#define ROWS (BATCH*SEQ)            // 32768
#define TM 64                       // rows per block (B-traffic = ROWS/TM * 8MB)
#define NBLK (ROWS/TM)              // 512 = 2 blocks/CU
#define RESPAD 132                  // res row stride (floats), 16B-aligned
#define CANDROW 67                  // cand row stride (uints)
#define OUT_ELEMS (BATCH*DIMS*SEQ)  // 4194304
#define IDX_ELEMS (BATCH*SEQ*NQ)    // 262144
#define LOSS_DIV (1.0f/33554432.0f) // 1/(Q*B*N*D)
#define FRAGQ ((size_t)4*256*64*8)  // halves per q-stage of bhi (1 MB)
#define SBIAS 384.0f                // key bias: keys = dot - csq/2 + 384, ~[240,450] > 0
#define WIN 2.0f                    // refine window (>> f16-dot err + f16-csv 0.125 + pack 0.125)

__device__ __forceinline__ unsigned umax_(unsigned a, unsigned b){ return a>b?a:b; }
__device__ __forceinline__ unsigned umin_(unsigned a, unsigned b){ return a<b?a:b; }

// async global->LDS DMA, 16 B/lane. LDS dest = wave-uniform base + lane*16.
// Zero VGPR cost -> regalloc cannot collapse the prefetch (round 6 failure).
__device__ __forceinline__ void gload16(const void* g, void* l) {
    __builtin_amdgcn_global_load_lds(
        (const __attribute__((address_space(1))) u32*)g,
        (__attribute__((address_space(3))) u32*)l, 16, 0, 0);
}

// ---------------- prep: csq[q][k] = sum_d cb^2 (f32) ; cinit_h = f16(384 - csq/2) ----------------
__global__ void prep_csq(const float* __restrict__ cb, float* __restrict__ csq,
                         _Float16* __restrict__ cinit_h) {
    int c = blockIdx.x * 256 + threadIdx.x;   // q*4096+k
    const float4* p = (const float4*)(cb + (size_t)c * DIMS);
    float s = 0.f;
#pragma unroll
    for (int i = 0; i < 32; ++i) {
        float4 v = p[i];
        s += v.x * v.x + v.y * v.y + v.z * v.z + v.w * v.w;
    }
    csq[c] = s;
    cinit_h[c] = (_Float16)(SBIAS - 0.5f * s);
}

// ---------------- prep: codebook -> f16 hi MFMA B-fragments (screen only) ----------------
// mfma_f32_16x16x32_f16 B-operand: lane l holds B[k=(l>>4)*8+j][n=l&15], j=0..7.
// Storage: frag g = ((q*4+kb)*256+nt)*64+lane at bhi + g*8 halves.
__global__ void prep_frags(const float* __restrict__ cb, _Float16* __restrict__ bhi,
                           float* __restrict__ loss_accum) {
    int g = blockIdx.x * 256 + threadIdx.x;   // 524288 total
    if (g == 0) loss_accum[0] = 0.f;
    int lane = g & 63;
    int nt   = (g >> 6) & 255;
    int kb   = (g >> 14) & 3;
    int q    = g >> 16;
    int code = nt * 16 + (lane & 15);
    int k0   = kb * 32 + ((lane >> 4) * 8);
    const float* src = cb + ((size_t)q * KCODES + code) * DIMS + k0;
    float4 v0 = *(const float4*)(src);
    float4 v1 = *(const float4*)(src + 4);
    half8 h;
    h[0] = (_Float16)v0.x; h[1] = (_Float16)v0.y; h[2] = (_Float16)v0.z; h[3] = (_Float16)v0.w;
    h[4] = (_Float16)v1.x; h[5] = (_Float16)v1.y; h[6] = (_Float16)v1.z; h[7] = (_Float16)v1.w;
    *(half8*)(bhi + (size_t)g * 8) = h;
}

// ---------------- one screen tile: counted-vmcnt depth-2 pipeline ----------------
// Invariant at entry: tile t landed in buf[t&1]; tile t+1's 4 loads outstanding.
// Body: read buf[t&1]; lgkm-drain (buf reusable); issue tile t+2 into buf[t&1];
// vmcnt(4) (t+1 landed, t+2 in flight); 16 MFMA; best-2 insert. No barriers.
__device__ __forceinline__ void screen_tile(
        int t, int ntBase, int lane, int col,
        char* stgw, const _Float16* __restrict__ bq, const _Float16* cql,
        const half8 (&ahi)[4][4], unsigned (&p1)[4][4], unsigned (&p2)[4][4]) {
    int nt = ntBase + t;
    const half8* sp = (const half8*)(stgw + ((t & 1) << 12) + (lane << 4));
    half8 b0 = sp[0], b1 = sp[64], b2 = sp[128], b3 = sp[192];
    float csv = (float)cql[nt * 16 + col];          // LDS f16, broadcast-friendly

    asm volatile("s_waitcnt lgkmcnt(0)" ::: "memory");   // reads done; buffer reusable

    {
        int ntn = ntBase + ((t + 2) & 63);
        char* dst = stgw + ((t & 1) << 12);
#pragma unroll
        for (int kb = 0; kb < 4; ++kb) {
            const _Float16* g = bq + (((size_t)(kb * 256 + ntn) * 64 + lane) << 3);
            gload16(g, dst + (kb << 10));
        }
    }
    asm volatile("s_waitcnt vmcnt(4)" ::: "memory");     // t+1 landed; t+2 in flight

    float4v acc[4];
#pragma unroll
    for (int mt = 0; mt < 4; ++mt) { acc[mt][0]=0.f; acc[mt][1]=0.f; acc[mt][2]=0.f; acc[mt][3]=0.f; }
    __builtin_amdgcn_s_setprio(1);
#pragma unroll
    for (int mt = 0; mt < 4; ++mt) acc[mt] = __builtin_amdgcn_mfma_f32_16x16x32_f16(ahi[mt][0], b0, acc[mt], 0, 0, 0);
#pragma unroll
    for (int mt = 0; mt < 4; ++mt) acc[mt] = __builtin_amdgcn_mfma_f32_16x16x32_f16(ahi[mt][1], b1, acc[mt], 0, 0, 0);
#pragma unroll
    for (int mt = 0; mt < 4; ++mt) acc[mt] = __builtin_amdgcn_mfma_f32_16x16x32_f16(ahi[mt][2], b2, acc[mt], 0, 0, 0);
#pragma unroll
    for (int mt = 0; mt < 4; ++mt) acc[mt] = __builtin_amdgcn_mfma_f32_16x16x32_f16(ahi[mt][3], b3, acc[mt], 0, 0, 0);
    __builtin_amdgcn_s_setprio(0);

    // key = dot + f16(384 - csq/2); pack idx into low 12 mantissa bits; best-2
    unsigned idxv = (unsigned)(nt * 16 + col);
#pragma unroll
    for (int mt = 0; mt < 4; ++mt)
#pragma unroll
        for (int r = 0; r < 4; ++r) {
            float key = acc[mt][r] + csv;
            unsigned p  = (__float_as_uint(key) & 0xFFFFF000u) | idxv;
            unsigned t1 = umin_(p1[mt][r], p);
            p1[mt][r]   = umax_(p1[mt][r], p);
            p2[mt][r]   = umax_(p2[mt][r], t1);
        }
}

// (256,2): VGPR cap 256 (generous; tight caps spill — round 2). Grid 512 = 2
// blocks/CU. Latency fix = counted vmcnt(4): tile t+2's loads stay in flight
// across tile t's compute (round 7's vmcnt(0)-per-tile was the anti-pattern).
__launch_bounds__(256, 2)
__global__ void rvq_main(const float* __restrict__ x, const float* __restrict__ cb,
                         const _Float16* __restrict__ bhi,
                         const float* __restrict__ csq, const _Float16* __restrict__ cinit_h,
                         float* __restrict__ out, float* __restrict__ loss_accum) {
    __shared__ float res[TM][RESPAD];                   // 33792 B
    __shared__ __align__(16) char stg[4][8192];         // per-wave 2x4KB dbuf (32768 B)
    __shared__ __align__(16) _Float16 cinq_lds[KCODES]; // f16 cinit for this q (8192 B)
    __shared__ float fbin[TM];                          // 256 B
    // overlays on stg (dead after screen loop, barrier-separated):
    unsigned (*cand)[CANDROW] = reinterpret_cast<unsigned (*)[CANDROW]>(&stg[0][0]); // 17152 B
    float* red = reinterpret_cast<float*>(&stg[0][0] + 20480);                       // 1024 B
    // static LDS = 75008 B -> 2 blocks/CU

    int tid  = threadIdx.x;
    int lane = tid & 63;
    int wv   = tid >> 6;
    int col  = lane & 15;
    int r0   = blockIdx.x * TM;
    int b    = r0 >> 12;                // / SEQ
    int n0   = r0 & (SEQ - 1);
    const float* xb = x + (size_t)b * DIMS * SEQ + n0;

    // load x[b][d][n0..n0+63] into res[n][d]
    {
        int d = tid >> 1, half = (tid & 1) * 32;
        const float* src = xb + (size_t)d * SEQ + half;
#pragma unroll
        for (int t4 = 0; t4 < 8; ++t4) {
            float4 v = *(const float4*)(src + t4 * 4);
            res[half + t4 * 4 + 0][d] = v.x;
            res[half + t4 * 4 + 1][d] = v.y;
            res[half + t4 * 4 + 2][d] = v.z;
            res[half + t4 * 4 + 3][d] = v.w;
        }
    }

    float lossacc = 0.f;
    int ntBase = wv * 64;
    char* stgw = &stg[wv][0];

    for (int q = 0; q < NQ; ++q) {
        __syncthreads();   // res stable; prev q's cand/stg reads done

        const _Float16* bq   = bhi + (size_t)q * FRAGQ;
        const _Float16* cq   = cinit_h + q * KCODES;
        const float*    csqq = csq + q * KCODES;

        // prologue DMAs in order: cinq slice (2) + tile0 (4) + tile1 (4) = 10
        {
            const _Float16* g0 = cq + wv * 1024 + lane * 8;
            gload16(g0,       (char*)cinq_lds + wv * 2048);
            gload16(g0 + 512, (char*)cinq_lds + wv * 2048 + 1024);
        }
#pragma unroll
        for (int tt = 0; tt < 2; ++tt) {
            char* dst = stgw + (tt << 12);
            int g = ntBase + tt;
#pragma unroll
            for (int kb = 0; kb < 4; ++kb)
                gload16(bq + (((size_t)(kb * 256 + g) * 64 + lane) << 3), dst + (kb << 10));
        }

        // build A fragments (hi f16) from res — ~600 cyc, covers prologue DMA
        half8 ahi[4][4];
#pragma unroll
        for (int mt = 0; mt < 4; ++mt)
#pragma unroll
        for (int kb = 0; kb < 4; ++kb) {
            int row = mt * 16 + col;
            int k0  = kb * 32 + (lane >> 4) * 8;
            float4 v0 = *(const float4*)&res[row][k0];
            float4 v1 = *(const float4*)&res[row][k0 + 4];
            half8 h;
            h[0] = (_Float16)v0.x; h[1] = (_Float16)v0.y; h[2] = (_Float16)v0.z; h[3] = (_Float16)v0.w;
            h[4] = (_Float16)v1.x; h[5] = (_Float16)v1.y; h[6] = (_Float16)v1.z; h[7] = (_Float16)v1.w;
            ahi[mt][kb] = h;
        }

        unsigned p1[4][4], p2[4][4];
#pragma unroll
        for (int mt = 0; mt < 4; ++mt)
#pragma unroll
        for (int r = 0; r < 4; ++r) { p1[mt][r] = 0u; p2[mt][r] = 0u; }

        // establish loop invariant: 6 oldest (cinq + tile0) landed, tile1 in flight
        asm volatile("s_waitcnt vmcnt(4)" ::: "memory");

        for (int t = 0; t < 64; t += 2) {
            screen_tile(t,     ntBase, lane, col, stgw, bq, cinq_lds, ahi, p1, p2);
            screen_tile(t + 1, ntBase, lane, col, stgw, bq, cinq_lds, ahi, p1, p2);
        }
        asm volatile("s_waitcnt vmcnt(0)" ::: "memory");   // drain tail prefetches
        __syncthreads();   // all waves done with stg -> cand overlay safe

        // pair-merge best-2 across (lane, lane^1) -> top-2-of-128 slices.
        // Sorted pairs A,B: n1=max(a1,b1); n2=max(min(a1,b1), max(a2,b2)).
#pragma unroll
        for (int mt = 0; mt < 4; ++mt)
#pragma unroll
        for (int r = 0; r < 4; ++r) {
            unsigned a1 = p1[mt][r], a2 = p2[mt][r];
            unsigned b1 = (unsigned)__shfl_xor((int)a1, 1, 64);
            unsigned b2 = (unsigned)__shfl_xor((int)a2, 1, 64);
            unsigned n1 = umax_(a1, b1);
            unsigned n2 = umax_(umin_(a1, b1), umax_(a2, b2));
            if ((lane & 1) == 0) {
                int row = mt * 16 + (lane >> 4) * 4 + r;
                int cc  = wv * 16 + (col >> 1) * 2;
                cand[row][cc]     = n1;
                cand[row][cc + 1] = n2;
            }
        }
        __syncthreads();

        // exact f32 refine: 4 threads/row scan 16 entries; entries within WIN
        // of the row max get an exact f32 dot (res in LDS, cb row in L2).
        {
            int row = tid >> 2, s = tid & 3;
            const unsigned* cp = &cand[row][s * 16];
            unsigned m = 0;
#pragma unroll
            for (int k = 0; k < 16; ++k) m = umax_(m, cp[k]);
            m = umax_(m, (unsigned)__shfl_xor((int)m, 1, 64));
            m = umax_(m, (unsigned)__shfl_xor((int)m, 2, 64));
            float thr = __uint_as_float(m) - WIN;
            float bk = -3.4e38f;
            int   bi = KCODES;
            const float4* rv = (const float4*)&res[row][0];
            for (int k = 0; k < 16; ++k) {
                unsigned e = cp[k];
                if (__uint_as_float(e) >= thr) {
                    int idx = (int)(e & 0xFFFu);
                    const float4* cv = (const float4*)(cb + ((size_t)q * KCODES + idx) * DIMS);
                    float acc = 0.f;
#pragma unroll
                    for (int jj = 0; jj < 32; ++jj) {
                        float4 c4 = cv[jj];
                        float4 r4 = rv[jj];
                        acc = fmaf(r4.x, c4.x, acc);
                        acc = fmaf(r4.y, c4.y, acc);
                        acc = fmaf(r4.z, c4.z, acc);
                        acc = fmaf(r4.w, c4.w, acc);
                    }
                    float key = acc - 0.5f * csqq[idx];
                    if (key > bk || (key == bk && idx < bi)) { bk = key; bi = idx; }
                }
            }
#pragma unroll
            for (int mask = 1; mask <= 2; mask <<= 1) {
                float ok = __shfl_xor(bk, mask, 64);
                int   oi = __shfl_xor(bi, mask, 64);
                if (ok > bk || (ok == bk && oi < bi)) { bk = ok; bi = oi; }
            }
            if (s == 0) {
                fbin[row] = (float)bi;
                out[OUT_ELEMS + (size_t)(r0 + row) * NQ + q] = (float)bi;  // index output
            }
        }
        __syncthreads();

        // residual update + commitment loss; contiguous 32-float chunk per thread
        {
            int row = tid >> 2, j = tid & 3;
            int bi = (int)fbin[row];
            const float* cv = cb + ((size_t)q * KCODES + bi) * DIMS + j * 32;
            float* rp = &res[row][j * 32];
#pragma unroll
            for (int t = 0; t < 8; ++t) {
                float4 c4 = *(const float4*)(cv + t * 4);
                float4 r4 = *(const float4*)(rp + t * 4);
                r4.x -= c4.x; lossacc = fmaf(r4.x, r4.x, lossacc);
                r4.y -= c4.y; lossacc = fmaf(r4.y, r4.y, lossacc);
                r4.z -= c4.z; lossacc = fmaf(r4.z, r4.z, lossacc);
                r4.w -= c4.w; lossacc = fmaf(r4.w, r4.w, lossacc);
                *(float4*)(rp + t * 4) = r4;
            }
        }
    }

    // loss reduction (red overlays stg; all stage/cand use is done)
    __syncthreads();
    red[tid] = lossacc;
    __syncthreads();
    for (int s = 128; s > 0; s >>= 1) {
        if (tid < s) red[tid] += red[tid + s];
        __syncthreads();
    }
    if (tid == 0) atomicAdd(loss_accum, red[0]);

    // quantized output: out = x - final_residual
    {
        int d = tid >> 1, half = (tid & 1) * 32;
        const float* src = xb + (size_t)d * SEQ + half;
        float* dst = out + (size_t)b * DIMS * SEQ + (size_t)d * SEQ + n0 + half;
#pragma unroll
        for (int t4 = 0; t4 < 8; ++t4) {
            float4 v = *(const float4*)(src + t4 * 4);
            v.x -= res[half + t4 * 4 + 0][d];
            v.y -= res[half + t4 * 4 + 1][d];
            v.z -= res[half + t4 * 4 + 2][d];
            v.w -= res[half + t4 * 4 + 3][d];
            *(float4*)(dst + t4 * 4) = v;
        }
    }
}

__global__ void finish_loss(const float* __restrict__ loss_accum, float* __restrict__ out) {
    out[OUT_ELEMS + IDX_ELEMS] = loss_accum[0] * LOSS_DIV;
}

extern "C" void kernel_launch(void* const* d_in, const int* in_sizes, int n_in,
                              void* d_out, int out_size, void* d_ws, size_t ws_size,
                              hipStream_t stream) {
    const float* x  = (const float*)d_in[0];
    const float* cb = (const float*)d_in[1];
    float* out = (float*)d_out;
    char*  ws  = (char*)d_ws;

    float*     loss_accum = (float*)ws;
    float*     csq     = (float*)(ws + 256);                       // 131072 B
    _Float16*  cinit_h = (_Float16*)(ws + 256 + 131072);           // 65536 B
    _Float16*  bhi     = (_Float16*)(ws + 256 + 131072 + 65536);   // 8 MB

    hipLaunchKernelGGL(prep_csq,   dim3(128),  dim3(256), 0, stream, cb, csq, cinit_h);
    hipLaunchKernelGGL(prep_frags, dim3(2048), dim3(256), 0, stream, cb, bhi, loss_accum);
    hipLaunchKernelGGL(rvq_main,   dim3(NBLK), dim3(256), 0, stream,
                       x, cb, bhi, csq, cinit_h, out, loss_accum);
    hipLaunchKernelGGL(finish_loss, dim3(1), dim3(1), 0, stream, loss_accum, out);
}

// Round 9
// 527.878 us; speedup vs baseline: 1.2465x; 1.0903x over previous
//
#include <hip/hip_runtime.h>

typedef _Float16 half8 __attribute__((ext_vector_type(8)));
typedef float    float4v __attribute__((ext_vector_type(4)));
typedef unsigned int u32;

#define NQ 8
#define KCODES 4096
#define DIMS 128
#define BATCH 8
#define SEQ 4096
#define ROWS (BATCH*SEQ)            // 32768
#define TM 64                       // rows per block
#define NBLK (ROWS/TM)              // 512 = 2 blocks/CU
#define RESPAD 132                  // res row stride (floats)
#define CANDROW 67                  // cand row stride (uints)
#define OUT_ELEMS (BATCH*DIMS*SEQ)  // 4194304
#define IDX_ELEMS (BATCH*SEQ*NQ)    // 262144
#define LOSS_DIV (1.0f/33554432.0f) // 1/(Q*B*N*D)
#define FRAGQ ((size_t)4*256*64*8)  // halves per q-stage of bhi (1 MB)
#define SBIAS 384.0f                // key bias: keys = dot - csq/2 + 384, ~[240,450] > 0
#define WIN 2.0f                    // refine window (>> f16 errs + pack trunc)

__device__ __forceinline__ unsigned umax_(unsigned a, unsigned b){ return a>b?a:b; }
__device__ __forceinline__ unsigned umin_(unsigned a, unsigned b){ return a<b?a:b; }

// async global->LDS DMA for the small cinq slice (vmcnt-tracked, issued first)
__device__ __forceinline__ void gload16(const void* g, void* l) {
    __builtin_amdgcn_global_load_lds(
        (const __attribute__((address_space(1))) u32*)g,
        (__attribute__((address_space(3))) u32*)l, 16, 0, 0);
}

// ---- asm-pinned B loads: 4 x dwordx4 into a named half8 quad ----
// "=v" outputs pin the destination registers: regalloc CANNOT rematerialize or
// sink these (round 6's C++ PF4 collapsed back to depth-1; VGPR stayed 128).
#define B_ISSUE(X0,X1,X2,X3,OFF)                                              \
    asm volatile("global_load_dwordx4 %0, %4, %8 offset:" #OFF "\n\t"         \
                 "global_load_dwordx4 %1, %5, %8 offset:" #OFF "\n\t"         \
                 "global_load_dwordx4 %2, %6, %8 offset:" #OFF "\n\t"         \
                 "global_load_dwordx4 %3, %7, %8 offset:" #OFF                \
                 : "=v"(X0), "=v"(X1), "=v"(X2), "=v"(X3)                     \
                 : "v"(vo0), "v"(vo1), "v"(vo2), "v"(vo3), "s"(bq))

// wait until <=8 vmem outstanding (= the named set, issued 3 tiles ago, landed).
// "+v" deps order the wait after the loads AND before the consuming MFMAs
// (rule #18: a bare asm wait gets hoisted past by register-only MFMA).
#define B_WAIT(X0,X1,X2,X3)                                                   \
    asm volatile("s_waitcnt vmcnt(8)"                                         \
                 : "+v"(X0), "+v"(X1), "+v"(X2), "+v"(X3))

// ---------------- prep: csq f32 ; cinit_h = f16(384 - csq/2) ----------------
__global__ void prep_csq(const float* __restrict__ cb, float* __restrict__ csq,
                         _Float16* __restrict__ cinit_h) {
    int c = blockIdx.x * 256 + threadIdx.x;
    const float4* p = (const float4*)(cb + (size_t)c * DIMS);
    float s = 0.f;
#pragma unroll
    for (int i = 0; i < 32; ++i) {
        float4 v = p[i];
        s += v.x * v.x + v.y * v.y + v.z * v.z + v.w * v.w;
    }
    csq[c] = s;
    cinit_h[c] = (_Float16)(SBIAS - 0.5f * s);
}

// ---------------- prep: codebook -> f16 MFMA B-fragments ----------------
__global__ void prep_frags(const float* __restrict__ cb, _Float16* __restrict__ bhi,
                           float* __restrict__ loss_accum) {
    int g = blockIdx.x * 256 + threadIdx.x;
    if (g == 0) loss_accum[0] = 0.f;
    int lane = g & 63;
    int nt   = (g >> 6) & 255;
    int kb   = (g >> 14) & 3;
    int q    = g >> 16;
    int code = nt * 16 + (lane & 15);
    int k0   = kb * 32 + ((lane >> 4) * 8);
    const float* src = cb + ((size_t)q * KCODES + code) * DIMS + k0;
    float4 v0 = *(const float4*)(src);
    float4 v1 = *(const float4*)(src + 4);
    half8 h;
    h[0] = (_Float16)v0.x; h[1] = (_Float16)v0.y; h[2] = (_Float16)v0.z; h[3] = (_Float16)v0.w;
    h[4] = (_Float16)v1.x; h[5] = (_Float16)v1.y; h[6] = (_Float16)v1.z; h[7] = (_Float16)v1.w;
    *(half8*)(bhi + (size_t)g * 8) = h;
}

// 16 MFMA + best-2 insert for one landed B set. acc init = csv (f16-rounded
// 384-csq/2): key add folded into the MFMA C-operand.
__device__ __forceinline__ void compute16(
        const half8& b0, const half8& b1, const half8& b2, const half8& b3,
        float csv, unsigned idxv, const half8 (&ahi)[4][4],
        unsigned (&p1)[4][4], unsigned (&p2)[4][4]) {
    float4v acc[4];
#pragma unroll
    for (int mt = 0; mt < 4; ++mt) { acc[mt][0]=csv; acc[mt][1]=csv; acc[mt][2]=csv; acc[mt][3]=csv; }
    __builtin_amdgcn_s_setprio(1);
#pragma unroll
    for (int mt = 0; mt < 4; ++mt) acc[mt] = __builtin_amdgcn_mfma_f32_16x16x32_f16(ahi[mt][0], b0, acc[mt], 0, 0, 0);
#pragma unroll
    for (int mt = 0; mt < 4; ++mt) acc[mt] = __builtin_amdgcn_mfma_f32_16x16x32_f16(ahi[mt][1], b1, acc[mt], 0, 0, 0);
#pragma unroll
    for (int mt = 0; mt < 4; ++mt) acc[mt] = __builtin_amdgcn_mfma_f32_16x16x32_f16(ahi[mt][2], b2, acc[mt], 0, 0, 0);
#pragma unroll
    for (int mt = 0; mt < 4; ++mt) acc[mt] = __builtin_amdgcn_mfma_f32_16x16x32_f16(ahi[mt][3], b3, acc[mt], 0, 0, 0);
    __builtin_amdgcn_s_setprio(0);
#pragma unroll
    for (int mt = 0; mt < 4; ++mt)
#pragma unroll
        for (int r = 0; r < 4; ++r) {
            unsigned p  = (__float_as_uint(acc[mt][r]) & 0xFFFFF000u) | idxv;
            unsigned t1 = umin_(p1[mt][r], p);
            p1[mt][r]   = umax_(p1[mt][r], p);
            p2[mt][r]   = umax_(p2[mt][r], t1);
        }
}

__launch_bounds__(256, 2)
__global__ void rvq_main(const float* __restrict__ x, const float* __restrict__ cb,
                         const _Float16* __restrict__ bhi,
                         const float* __restrict__ csq, const _Float16* __restrict__ cinit_h,
                         float* __restrict__ out, float* __restrict__ loss_accum) {
    __shared__ float    res[TM][RESPAD];                   // 33792 B
    __shared__ __align__(16) _Float16 cinq_lds[KCODES];    // 8192 B
    __shared__ unsigned cand[TM][CANDROW];                 // 17152 B
    __shared__ float    fbin[TM];                          // 256 B
    __shared__ float    red[256];                          // 1024 B
    // static LDS ~= 60.4 KB -> 2 blocks/CU

    int tid  = threadIdx.x;
    int lane = tid & 63;
    int wv   = tid >> 6;
    int col  = lane & 15;
    int r0   = blockIdx.x * TM;
    int b    = r0 >> 12;
    int n0   = r0 & (SEQ - 1);
    const float* xb = x + (size_t)b * DIMS * SEQ + n0;

    // load x[b][d][n0..n0+63] into res[n][d]
    {
        int d = tid >> 1, half = (tid & 1) * 32;
        const float* src = xb + (size_t)d * SEQ + half;
#pragma unroll
        for (int t4 = 0; t4 < 8; ++t4) {
            float4 v = *(const float4*)(src + t4 * 4);
            res[half + t4 * 4 + 0][d] = v.x;
            res[half + t4 * 4 + 1][d] = v.y;
            res[half + t4 * 4 + 2][d] = v.z;
            res[half + t4 * 4 + 3][d] = v.w;
        }
    }

    float lossacc = 0.f;
    int ntBase = wv * 64;

    for (int q = 0; q < NQ; ++q) {
        // res writes are LDS -> lgkm drain + raw barrier. (A full __syncthreads
        // would emit vmcnt(0) too; harmless here but keep the pattern tight.)
        asm volatile("s_waitcnt lgkmcnt(0)" ::: "memory");
        __builtin_amdgcn_s_barrier();

        const _Float16* bq   = bhi + (size_t)q * FRAGQ;
        const _Float16* cq   = cinit_h + q * KCODES;
        const float*    csqq = csq + q * KCODES;

        // cinq slice -> LDS first (oldest in vmcnt queue; wave-private region)
        {
            const _Float16* g0 = cq + wv * 1024 + lane * 8;
            gload16(g0,       (char*)cinq_lds + wv * 2048);
            gload16(g0 + 512, (char*)cinq_lds + wv * 2048 + 1024);
        }

        // B voffsets point at tile ntBase+3 (loop invariant: voffs = t+3 at tile t)
        u32 vo0, vo1, vo2, vo3;
        {
            u32 base = (u32)(((ntBase + 3) * 64 + lane) << 4);
            vo0 = base;
            vo1 = base + (256u * 64u * 16u);
            vo2 = base + (512u * 64u * 16u);
            vo3 = base + (768u * 64u * 16u);
        }
        half8 a0,a1,a2,a3, b0,b1,b2,b3, c0,c1,c2,c3, d0,d1,d2,d3;
        B_ISSUE(a0,a1,a2,a3, -3072);   // tile ntBase+0
        B_ISSUE(b0,b1,b2,b3, -2048);   // tile ntBase+1
        B_ISSUE(c0,c1,c2,c3, -1024);   // tile ntBase+2
        // outstanding: cinq(2) + 12 = 14

        // build A fragments (covers the prologue loads)
        half8 ahi[4][4];
#pragma unroll
        for (int mt = 0; mt < 4; ++mt)
#pragma unroll
        for (int kb = 0; kb < 4; ++kb) {
            int row = mt * 16 + col;
            int k0  = kb * 32 + (lane >> 4) * 8;
            float4 v0 = *(const float4*)&res[row][k0];
            float4 v1 = *(const float4*)&res[row][k0 + 4];
            half8 h;
            h[0] = (_Float16)v0.x; h[1] = (_Float16)v0.y; h[2] = (_Float16)v0.z; h[3] = (_Float16)v0.w;
            h[4] = (_Float16)v1.x; h[5] = (_Float16)v1.y; h[6] = (_Float16)v1.z; h[7] = (_Float16)v1.w;
            ahi[mt][kb] = h;
        }

        unsigned p1[4][4], p2[4][4];
#pragma unroll
        for (int mt = 0; mt < 4; ++mt)
#pragma unroll
        for (int r = 0; r < 4; ++r) { p1[mt][r] = 0u; p2[mt][r] = 0u; }

        unsigned idx0 = (unsigned)(ntBase * 16 + col);

        // 16 super-iters x 4 tiles; depth-3 pinned pipeline.
        // Per tile: vmcnt(8) [set landed] -> issue t+3 -> compute.
        for (int ii = 0; ii < 16; ++ii) {
            int t = ii * 4;
            float cs0 = (float)cinq_lds[(ntBase + t + 0) * 16 + col];
            float cs1 = (float)cinq_lds[(ntBase + t + 1) * 16 + col];
            float cs2 = (float)cinq_lds[(ntBase + t + 2) * 16 + col];
            float cs3 = (float)cinq_lds[(ntBase + t + 3) * 16 + col];

            B_WAIT(a0,a1,a2,a3);
            B_ISSUE(d0,d1,d2,d3, 0);        // tile t+3
            compute16(a0,a1,a2,a3, cs0, idx0 + (unsigned)(t+0)*16u, ahi, p1, p2);

            B_WAIT(b0,b1,b2,b3);
            B_ISSUE(a0,a1,a2,a3, 1024);     // tile t+4
            compute16(b0,b1,b2,b3, cs1, idx0 + (unsigned)(t+1)*16u, ahi, p1, p2);

            B_WAIT(c0,c1,c2,c3);
            B_ISSUE(b0,b1,b2,b3, 2048);     // tile t+5
            compute16(c0,c1,c2,c3, cs2, idx0 + (unsigned)(t+2)*16u, ahi, p1, p2);

            B_WAIT(d0,d1,d2,d3);
            B_ISSUE(c0,c1,c2,c3, 3072);     // tile t+6
            compute16(d0,d1,d2,d3, cs3, idx0 + (unsigned)(t+3)*16u, ahi, p1, p2);

            vo0 += 4096; vo1 += 4096; vo2 += 4096; vo3 += 4096;
        }
        // 12 tail loads (tiles 64..66, reads run into next q / pad region) are
        // dead; the __syncthreads below drains them.
        __syncthreads();

        // pair-merge best-2 across (lane, lane^1) -> top-2-of-128 slices
#pragma unroll
        for (int mt = 0; mt < 4; ++mt)
#pragma unroll
        for (int r = 0; r < 4; ++r) {
            unsigned q1 = p1[mt][r], q2 = p2[mt][r];
            unsigned o1 = (unsigned)__shfl_xor((int)q1, 1, 64);
            unsigned o2 = (unsigned)__shfl_xor((int)q2, 1, 64);
            unsigned n1 = umax_(q1, o1);
            unsigned n2 = umax_(umin_(q1, o1), umax_(q2, o2));
            if ((lane & 1) == 0) {
                int row = mt * 16 + (lane >> 4) * 4 + r;
                int cc  = wv * 16 + (col >> 1) * 2;
                cand[row][cc]     = n1;
                cand[row][cc + 1] = n2;
            }
        }
        __syncthreads();

        // exact f32 refine: 4 threads/row scan 16 entries; within-WIN entries
        // get an exact f32 dot (res in LDS, cb row in L2)
        {
            int row = tid >> 2, s = tid & 3;
            const unsigned* cp = &cand[row][s * 16];
            unsigned m = 0;
#pragma unroll
            for (int k = 0; k < 16; ++k) m = umax_(m, cp[k]);
            m = umax_(m, (unsigned)__shfl_xor((int)m, 1, 64));
            m = umax_(m, (unsigned)__shfl_xor((int)m, 2, 64));
            float thr = __uint_as_float(m) - WIN;
            float bk = -3.4e38f;
            int   bi = KCODES;
            const float4* rv = (const float4*)&res[row][0];
            for (int k = 0; k < 16; ++k) {
                unsigned e = cp[k];
                if (__uint_as_float(e) >= thr) {
                    int idx = (int)(e & 0xFFFu);
                    const float4* cv = (const float4*)(cb + ((size_t)q * KCODES + idx) * DIMS);
                    float acc = 0.f;
#pragma unroll
                    for (int jj = 0; jj < 32; ++jj) {
                        float4 c4 = cv[jj];
                        float4 r4 = rv[jj];
                        acc = fmaf(r4.x, c4.x, acc);
                        acc = fmaf(r4.y, c4.y, acc);
                        acc = fmaf(r4.z, c4.z, acc);
                        acc = fmaf(r4.w, c4.w, acc);
                    }
                    float key = acc - 0.5f * csqq[idx];
                    if (key > bk || (key == bk && idx < bi)) { bk = key; bi = idx; }
                }
            }
#pragma unroll
            for (int mask = 1; mask <= 2; mask <<= 1) {
                float ok = __shfl_xor(bk, mask, 64);
                int   oi = __shfl_xor(bi, mask, 64);
                if (ok > bk || (ok == bk && oi < bi)) { bk = ok; bi = oi; }
            }
            if (s == 0) {
                fbin[row] = (float)bi;
                out[OUT_ELEMS + (size_t)(r0 + row) * NQ + q] = (float)bi;
            }
        }
        __syncthreads();

        // residual update + commitment loss; contiguous 32-float chunk/thread
        {
            int row = tid >> 2, j = tid & 3;
            int bi = (int)fbin[row];
            const float* cv = cb + ((size_t)q * KCODES + bi) * DIMS + j * 32;
            float* rp = &res[row][j * 32];
#pragma unroll
            for (int t = 0; t < 8; ++t) {
                float4 c4 = *(const float4*)(cv + t * 4);
                float4 r4 = *(const float4*)(rp + t * 4);
                r4.x -= c4.x; lossacc = fmaf(r4.x, r4.x, lossacc);
                r4.y -= c4.y; lossacc = fmaf(r4.y, r4.y, lossacc);
                r4.z -= c4.z; lossacc = fmaf(r4.z, r4.z, lossacc);
                r4.w -= c4.w; lossacc = fmaf(r4.w, r4.w, lossacc);
                *(float4*)(rp + t * 4) = r4;
            }
        }
    }

    // loss reduction
    __syncthreads();
    red[tid] = lossacc;
    __syncthreads();
    for (int s = 128; s > 0; s >>= 1) {
        if (tid < s) red[tid] += red[tid + s];
        __syncthreads();
    }
    if (tid == 0) atomicAdd(loss_accum, red[0]);

    // quantized output: out = x - final_residual
    {
        int d = tid >> 1, half = (tid & 1) * 32;
        const float* src = xb + (size_t)d * SEQ + half;
        float* dst = out + (size_t)b * DIMS * SEQ + (size_t)d * SEQ + n0 + half;
#pragma unroll
        for (int t4 = 0; t4 < 8; ++t4) {
            float4 v = *(const float4*)(src + t4 * 4);
            v.x -= res[half + t4 * 4 + 0][d];
            v.y -= res[half + t4 * 4 + 1][d];
            v.z -= res[half + t4 * 4 + 2][d];
            v.w -= res[half + t4 * 4 + 3][d];
            *(float4*)(dst + t4 * 4) = v;
        }
    }
}

__global__ void finish_loss(const float* __restrict__ loss_accum, float* __restrict__ out) {
    out[OUT_ELEMS + IDX_ELEMS] = loss_accum[0] * LOSS_DIV;
}

extern "C" void kernel_launch(void* const* d_in, const int* in_sizes, int n_in,
                              void* d_out, int out_size, void* d_ws, size_t ws_size,
                              hipStream_t stream) {
    const float* x  = (const float*)d_in[0];
    const float* cb = (const float*)d_in[1];
    float* out = (float*)d_out;
    char*  ws  = (char*)d_ws;

    float*     loss_accum = (float*)ws;
    float*     csq     = (float*)(ws + 256);                       // 131072 B
    _Float16*  cinit_h = (_Float16*)(ws + 256 + 131072);           // 65536 B
    _Float16*  bhi     = (_Float16*)(ws + 256 + 131072 + 65536);   // 8 MB (+16KB
                                 // tail pad: last-q prefetch overreach lands here)

    hipLaunchKernelGGL(prep_csq,   dim3(128),  dim3(256), 0, stream, cb, csq, cinit_h);
    hipLaunchKernelGGL(prep_frags, dim3(2048), dim3(256), 0, stream, cb, bhi, loss_accum);
    hipLaunchKernelGGL(rvq_main,   dim3(NBLK), dim3(256), 0, stream,
                       x, cb, bhi, csq, cinit_h, out, loss_accum);
    hipLaunchKernelGGL(finish_loss, dim3(1), dim3(1), 0, stream, loss_accum, out);
}